// Round 15
// baseline (315.337 us; speedup 1.0000x reference)
//
#include <hip/hip_runtime.h>

#define E0     300000
#define E1     75000
#define NSRC0  50000
#define NDST0  20000
#define NDST1  5000
#define EMB    128
#define HID    256
#define NOUT   16

#define NPB        40     // nodes per embed block (1250 * 40 = 50000 exactly)
#define TILE_SHIFT 12     // 4096-row vocab tiles; tiles 0..12
#define NEMB_BLK   (NSRC0 / NPB)          // 1250
#define NBKT_BLK   ((E0 + 255) / 256)     // 1172

#define X0S  32.0f        // fp8 pre-scale for x0  (undone in agg1)
#define H1S  64.0f        // fp8 pre-scale for h1  (undone in agg2)

typedef __attribute__((ext_vector_type(8))) short bf16x8;   // MFMA A/B frag (4 VGPRs)
typedef __attribute__((ext_vector_type(4))) float f32x4;    // MFMA C/D frag
typedef __attribute__((ext_vector_type(2))) float f32x2;

// ---- bf16 helpers ----
__device__ __forceinline__ unsigned short f2bf(float f) {
    unsigned u = __float_as_uint(f);
    return (unsigned short)((u + 0x7FFFu + ((u >> 16) & 1u)) >> 16);
}
__device__ __forceinline__ unsigned pack2(float a, float b) {
    return (unsigned)f2bf(a) | ((unsigned)f2bf(b) << 16);
}
// ---- fp8 e4m3 helpers (HW cvt) ----
__device__ __forceinline__ unsigned pack4_fp8(float a0, float a1, float a2, float a3) {
    unsigned p = 0;
    p = __builtin_amdgcn_cvt_pk_fp8_f32(a0, a1, p, false);   // bytes 0,1
    p = __builtin_amdgcn_cvt_pk_fp8_f32(a2, a3, p, true);    // bytes 2,3
    return p;
}
__device__ __forceinline__ unsigned char f2fp8(float v) {
    unsigned p = __builtin_amdgcn_cvt_pk_fp8_f32(v, v, 0, false);
    return (unsigned char)(p & 0xFF);
}
// unpack 4 fp8 bytes -> two float2 (packed HW cvt when available)
#if __has_builtin(__builtin_amdgcn_cvt_pk_f32_fp8)
__device__ __forceinline__ f32x2 up_lo(unsigned v) { return __builtin_amdgcn_cvt_pk_f32_fp8(v, false); }
__device__ __forceinline__ f32x2 up_hi(unsigned v) { return __builtin_amdgcn_cvt_pk_f32_fp8(v, true); }
#else
__device__ __forceinline__ f32x2 up_lo(unsigned v) {
    f32x2 r; r.x = __builtin_amdgcn_cvt_f32_fp8(v, 0); r.y = __builtin_amdgcn_cvt_f32_fp8(v, 1); return r;
}
__device__ __forceinline__ f32x2 up_hi(unsigned v) {
    f32x2 r; r.x = __builtin_amdgcn_cvt_f32_fp8(v, 2); r.y = __builtin_amdgcn_cvt_f32_fp8(v, 3); return r;
}
#endif

// ---------------- prep: table->fp8, W1^T/W2^T->bf16, degree histograms ----------------
__global__ void prep_kernel(const float* __restrict__ wt, unsigned char* __restrict__ wt8,
                            const float* __restrict__ W1, unsigned short* __restrict__ W1Tb,
                            const float* __restrict__ W2, unsigned short* __restrict__ W2Tb,
                            const int* __restrict__ src0, const int* __restrict__ dst0,
                            const int* __restrict__ src1, const int* __restrict__ dst1,
                            int* cnt0, int* cnt1, int* degO0, int* degO1) {
    int i = blockIdx.x * blockDim.x + threadIdx.x;
    if (i < NSRC0 * EMB / 8) {            // 800000: pack 8 floats -> 8 fp8
        const float4* in = (const float4*)wt;
        float4 v0 = in[i * 2], v1 = in[i * 2 + 1];
        uint2 o;
        o.x = pack4_fp8(v0.x, v0.y, v0.z, v0.w);
        o.y = pack4_fp8(v1.x, v1.y, v1.z, v1.w);
        ((uint2*)wt8)[i] = o;
    }
    if (i < EMB * HID) {                  // W1[128][256] -> W1T bf16 [256][128]
        int n = i & 255, k = i >> 8;
        W1Tb[n * 128 + k] = f2bf(W1[i]);
    }
    if (i < HID * NOUT) {                 // W2[256][16] -> W2T bf16 [16][256]
        int n = i & 15, k = i >> 4;
        W2Tb[n * 256 + k] = f2bf(W2[i]);
    }
    if (i < E0) {
        atomicAdd(&cnt0[dst0[i]], 1);
        atomicAdd(&degO0[src0[i]], 1);
    }
    if (i < E1) {
        atomicAdd(&cnt1[dst1[i]], 1);
        atomicAdd(&degO1[src1[i]], 1);
    }
}

// ---------------- exclusive scan (2 blocks x 1024 threads, own dispatch) --------------
__device__ void scan_body(const int* __restrict__ cnt, int n,
                          int* __restrict__ off, int* __restrict__ cur) {
    __shared__ int sums[1024];
    int t = threadIdx.x;
    int chunk = (n + 1023) / 1024;
    int lo = t * chunk, hi = min(lo + chunk, n);
    int s = 0;
    for (int i = lo; i < hi; ++i) s += cnt[i];
    sums[t] = s;
    __syncthreads();
    for (int d = 1; d < 1024; d <<= 1) {
        int x = (t >= d) ? sums[t - d] : 0;
        __syncthreads();
        sums[t] += x;
        __syncthreads();
    }
    int run = (t == 0) ? 0 : sums[t - 1];
    for (int i = lo; i < hi; ++i) {
        off[i] = run; cur[i] = run;
        run += cnt[i];
    }
    if (t == 1023) off[n] = run;
}

__global__ void scan_kernel(const int* cnt0, int* off0, int* cur0,
                            const int* cnt1, int* off1, int* cur1) {
    if (blockIdx.x == 0) scan_body(cnt0, NDST0, off0, cur0);
    else                 scan_body(cnt1, NDST1, off1, cur1);
}

// ---------------- embed (blocks 0..1249) + edge bucket (blocks 1250..2421) fused ------
// Embed is TILE-MAJOR: each wave holds 5 node-accumulators in registers and sweeps
// vocab tiles once per pass (tile-outer, node-inner), so all resident waves converge
// on the same tile at any instant -> table tile stays L2-resident.
__global__ void embed_bucket_kernel(const int* __restrict__ user_word,
                                    const unsigned char* __restrict__ wt8,
                                    const int* __restrict__ degO0,
                                    unsigned char* __restrict__ x0f,
                                    const int* __restrict__ src0, const int* __restrict__ dst0,
                                    const int* __restrict__ src1, const int* __restrict__ dst1,
                                    int* cur0, int* cur1, int* esrc0, int* esrc1) {
    if (blockIdx.x >= NEMB_BLK) {        // ---- bucket part ----
        int i = (blockIdx.x - NEMB_BLK) * 256 + threadIdx.x;
        if (i < E0) {
            int p = atomicAdd(&cur0[dst0[i]], 1);
            esrc0[p] = src0[i];
        }
        if (i < E1) {
            int p = atomicAdd(&cur1[dst1[i]], 1);
            esrc1[p] = src1[i];
        }
        return;
    }
    // ---- embed part ----
    __shared__ int raw[NPB * 50];
    __shared__ int srt[NPB * 50];
    __shared__ int cnt[NPB * 17];        // per-node tile END offsets after scatter
    int t = threadIdx.x;
    int base = blockIdx.x * NPB * 50;
    for (int j = t; j < NPB * 50; j += 256)
        raw[j] = user_word[base + j];
    for (int j = t; j < NPB * 17; j += 256)
        cnt[j] = 0;
    __syncthreads();
    if (t < NPB) {                                // 1 thread sorts 1 node (in LDS)
        int* c = cnt + t * 17;
        const int* r = raw + t * 50;
        for (int j = 0; j < 50; ++j) c[r[j] >> TILE_SHIFT]++;
        int run = 0;
        for (int b = 0; b < 13; ++b) { int v = c[b]; c[b] = run; run += v; }
        int* o = srt + t * 50;
        for (int j = 0; j < 50; ++j) { int v = r[j]; o[c[v >> TILE_SHIFT]++] = v; }
        // post: c[b] = end offset of tile b for this node
    }
    __syncthreads();
    int w = t >> 6;                               // wave 0..3: nodes [w*10, w*10+10)
    int lane = t & 63, half = lane >> 5, l = lane & 31;
    const unsigned* wt4 = (const unsigned*)wt8;   // row = 32 uints
    #pragma unroll
    for (int pass = 0; pass < 2; ++pass) {        // 2 passes x 5 nodes
        int n0 = w * 10 + pass * 5;
        f32x2 a01[5], a23[5];
        #pragma unroll
        for (int k = 0; k < 5; ++k) { a01[k] = (f32x2){0.f, 0.f}; a23[k] = (f32x2){0.f, 0.f}; }
        for (int b = 0; b < 13; ++b) {            // tile-outer sweep
            #pragma unroll
            for (int k = 0; k < 5; ++k) {         // node-inner
                int n = n0 + k;
                int js = b ? cnt[n * 17 + b - 1] : 0;
                int je = cnt[n * 17 + b];
                const int* id = srt + n * 50;
                for (int j = js + half; j < je; j += 2) {   // halves split the run
                    unsigned v = wt4[id[j] * 32 + l];
                    a01[k] += up_lo(v); a23[k] += up_hi(v);
                }
            }
        }
        #pragma unroll
        for (int k = 0; k < 5; ++k) {
            a01[k].x += __shfl_down(a01[k].x, 32); a01[k].y += __shfl_down(a01[k].y, 32);
            a23[k].x += __shfl_down(a23[k].x, 32); a23[k].y += __shfl_down(a23[k].y, 32);
            if (half == 0) {
                int node = blockIdx.x * NPB + n0 + k;
                float s = rsqrtf(fmaxf((float)degO0[node], 1.0f)) * (0.02f * X0S);
                ((unsigned*)x0f)[node * 32 + l] =
                    pack4_fp8(a01[k].x * s, a01[k].y * s, a23[k].x * s, a23[k].y * s);
            }
        }
    }
}

// ---------------- layer-1 gather-aggregate (fp8 in, bf16 out, 1 wave/dst) ----------
__global__ void agg1_kernel(const int* __restrict__ off0, const int* __restrict__ esrc0,
                            const unsigned char* __restrict__ x0f,
                            unsigned short* __restrict__ agg1b) {
    int d = blockIdx.x;
    int t = threadIdx.x;               // 0..63
    int half = t >> 5, l = t & 31;
    int lo = off0[d], hi = off0[d + 1];
    const unsigned* x4 = (const unsigned*)x0f;     // row = 32 uints
    f32x2 a01 = {0.f, 0.f}, a23 = {0.f, 0.f};
    for (int j = lo + half; j < hi; j += 2) {
        unsigned v = x4[esrc0[j] * 32 + l];
        a01 += up_lo(v); a23 += up_hi(v);
    }
    a01.x += __shfl_down(a01.x, 32); a01.y += __shfl_down(a01.y, 32);
    a23.x += __shfl_down(a23.x, 32); a23.y += __shfl_down(a23.y, 32);
    if (half == 0) {
        float sc = rsqrtf(fmaxf((float)(hi - lo), 1.0f)) * (1.0f / X0S);
        uint2 o; o.x = pack2(a01.x * sc, a01.y * sc); o.y = pack2(a23.x * sc, a23.y * sc);
        ((uint2*)agg1b)[d * 32 + l] = o;
    }
}

// ---------------- GEMM1 via MFMA: h1 = relu(agg1 @ W1 + b1) * rsqrt(degO1), fp8 out --
__global__ void gemm1_kernel(const unsigned short* __restrict__ agg1b,
                             const int* __restrict__ degO1,
                             const unsigned short* __restrict__ W1Tb,
                             const float* __restrict__ b1,
                             unsigned char* __restrict__ h1f) {
    __shared__ float s_out[16];
    int t = threadIdx.x;
    int row0 = blockIdx.x * 16;
    if (t < 16) s_out[t] = rsqrtf(fmaxf((float)degO1[row0 + t], 1.0f)) * H1S;
    __syncthreads();
    int w = t >> 6, lane = t & 63;
    int m = lane & 15, quad = lane >> 4;
    const unsigned short* abase = agg1b + (row0 + m) * 128 + quad * 8;
    bf16x8 afr[4];
    #pragma unroll
    for (int ks = 0; ks < 4; ++ks)
        afr[ks] = *(const bf16x8*)(abase + ks * 32);
    #pragma unroll
    for (int ct = 0; ct < 4; ++ct) {
        int gcol0 = (w * 4 + ct) * 16;
        const unsigned short* bbase = W1Tb + (gcol0 + m) * 128 + quad * 8;
        f32x4 acc = {0.f, 0.f, 0.f, 0.f};
        #pragma unroll
        for (int ks = 0; ks < 4; ++ks) {
            bf16x8 bfr = *(const bf16x8*)(bbase + ks * 32);
            acc = __builtin_amdgcn_mfma_f32_16x16x32_bf16(afr[ks], bfr, acc, 0, 0, 0);
        }
        int gcol = gcol0 + m;
        float bb = b1[gcol];
        #pragma unroll
        for (int reg = 0; reg < 4; ++reg) {
            int row = quad * 4 + reg;
            h1f[(row0 + row) * 256 + gcol] = f2fp8(fmaxf(acc[reg] + bb, 0.f) * s_out[row]);
        }
    }
}

// ---------------- layer-2 gather-aggregate (fp8 in, bf16 out, 1 wave/dst) -----------
__global__ void agg2_kernel(const int* __restrict__ off1, const int* __restrict__ esrc1,
                            const unsigned char* __restrict__ h1f,
                            unsigned short* __restrict__ agg2b) {
    int d = blockIdx.x;
    int l = threadIdx.x;               // 0..63
    int lo = off1[d], hi = off1[d + 1];
    const unsigned* h4 = (const unsigned*)h1f;     // row = 64 uints
    f32x2 a01 = {0.f, 0.f}, a23 = {0.f, 0.f};
    int j = lo;
    for (; j + 1 < hi; j += 2) {
        unsigned v0 = h4[esrc1[j] * 64 + l];
        unsigned v1 = h4[esrc1[j + 1] * 64 + l];
        a01 += up_lo(v0) + up_lo(v1);
        a23 += up_hi(v0) + up_hi(v1);
    }
    if (j < hi) {
        unsigned v = h4[esrc1[j] * 64 + l];
        a01 += up_lo(v); a23 += up_hi(v);
    }
    float sc = rsqrtf(fmaxf((float)(hi - lo), 1.0f)) * (1.0f / H1S);
    uint2 o; o.x = pack2(a01.x * sc, a01.y * sc); o.y = pack2(a23.x * sc, a23.y * sc);
    ((uint2*)agg2b)[d * 64 + l] = o;
}

// ---------------- GEMM2 via MFMA: out = relu(agg2 @ W2 + b2) (+ labels) --------------
__global__ void gemm2_kernel(const unsigned short* __restrict__ agg2b,
                             const unsigned short* __restrict__ W2Tb,
                             const float* __restrict__ b2,
                             const int* __restrict__ labels,
                             float* __restrict__ out) {
    int lane = threadIdx.x;            // 0..63
    int row0 = blockIdx.x * 16;
    int m = lane & 15, quad = lane >> 4;
    int arow = min(row0 + m, NDST1 - 1);           // clamp OOB reads (last block)
    const unsigned short* abase = agg2b + arow * 256 + quad * 8;
    const unsigned short* bbase = W2Tb + m * 256 + quad * 8;
    f32x4 acc = {0.f, 0.f, 0.f, 0.f};
    #pragma unroll
    for (int ks = 0; ks < 8; ++ks) {
        bf16x8 af = *(const bf16x8*)(abase + ks * 32);
        bf16x8 bf = *(const bf16x8*)(bbase + ks * 32);
        acc = __builtin_amdgcn_mfma_f32_16x16x32_bf16(af, bf, acc, 0, 0, 0);
    }
    float bb = b2[m];
    #pragma unroll
    for (int reg = 0; reg < 4; ++reg) {
        int row = row0 + quad * 4 + reg;
        if (row < NDST1)
            out[row * NOUT + m] = fmaxf(acc[reg] + bb, 0.f);
    }
    if (lane < 16 && row0 + lane < NDST1)
        out[NDST1 * NOUT + row0 + lane] = (float)labels[row0 + lane];
}

extern "C" void kernel_launch(void* const* d_in, const int* in_sizes, int n_in,
                              void* d_out, int out_size, void* d_ws, size_t ws_size,
                              hipStream_t stream) {
    const int*   user_word  = (const int*)d_in[0];
    const int*   labels     = (const int*)d_in[1];
    const int*   src0       = (const int*)d_in[2];
    const int*   dst0       = (const int*)d_in[3];
    const int*   src1       = (const int*)d_in[4];
    const int*   dst1       = (const int*)d_in[5];
    const float* word_table = (const float*)d_in[6];
    const float* W1         = (const float*)d_in[7];
    const float* b1         = (const float*)d_in[8];
    const float* W2         = (const float*)d_in[9];
    const float* b2         = (const float*)d_in[10];

    int* iws = (int*)d_ws;
    int* cnt0  = iws;            // 20000  ┐
    int* cnt1  = iws + 20000;    //  5000  │ zeroed (95000 ints)
    int* degO0 = iws + 25000;    // 50000  │
    int* degO1 = iws + 75000;    // 20000  ┘
    int* off0  = iws + 95000;    // 20001
    int* off1  = iws + 115001;   //  5001
    int* cur0  = iws + 120002;   // 20000
    int* cur1  = iws + 140002;   //  5000
    int* esrc0 = iws + 145002;   // 300000
    int* esrc1 = iws + 445002;   // 75000   (end 520002; pad to 520004)
    unsigned char*  wt8   = (unsigned char*)(iws + 520004);   // 6.4M fp8  = 1.6M ints
    unsigned char*  x0f   = (unsigned char*)(iws + 2120004);  // 6.4M fp8  = 1.6M ints
    unsigned char*  h1f   = (unsigned char*)(iws + 3720004);  // 5.12M fp8 = 1.28M ints
    unsigned short* agg1b = (unsigned short*)(iws + 5000004); // 2.56M bf16 = 1.28M ints
    unsigned short* agg2b = (unsigned short*)(iws + 6280004); // 1.28M bf16 = 640K ints
    unsigned short* W1Tb  = (unsigned short*)(iws + 6920004); // 32768 bf16
    unsigned short* W2Tb  = (unsigned short*)(iws + 6936388); // 4096 bf16 (end ≈ 27.8 MB)

    hipMemsetAsync(iws, 0, 95000 * sizeof(int), stream);

    prep_kernel<<<(NSRC0 * EMB / 8 + 255) / 256, 256, 0, stream>>>(
        word_table, wt8, W1, W1Tb, W2, W2Tb,
        src0, dst0, src1, dst1, cnt0, cnt1, degO0, degO1);
    scan_kernel<<<2, 1024, 0, stream>>>(cnt0, off0, cur0, cnt1, off1, cur1);
    embed_bucket_kernel<<<NEMB_BLK + NBKT_BLK, 256, 0, stream>>>(
        user_word, wt8, degO0, x0f,
        src0, dst0, src1, dst1, cur0, cur1, esrc0, esrc1);
    agg1_kernel<<<NDST0, 64, 0, stream>>>(off0, esrc0, x0f, agg1b);
    gemm1_kernel<<<NDST0 / 16, 256, 0, stream>>>(agg1b, degO1, W1Tb, b1, h1f);
    agg2_kernel<<<NDST1, 64, 0, stream>>>(off1, esrc1, h1f, agg2b);
    gemm2_kernel<<<(NDST1 + 15) / 16, 64, 0, stream>>>(agg2b, W2Tb, b2, labels, (float*)d_out);
}

// Round 16
// 268.418 us; speedup vs baseline: 1.1748x; 1.1748x over previous
//
#include <hip/hip_runtime.h>

#define E0     300000
#define E1     75000
#define NSRC0  50000
#define NDST0  20000
#define NDST1  5000
#define EMB    128
#define HID    256
#define NOUT   16

#define NPB        40     // nodes per embed block (1250 * 40 = 50000 exactly)
#define TILE_SHIFT 12     // 4096-row vocab tiles; tiles 0..12
#define NEMB_BLK   (NSRC0 / NPB)          // 1250

#define X0S  32.0f        // fp8 pre-scale for x0  (undone in agg1)
#define H1S  64.0f        // fp8 pre-scale for h1  (undone in agg2)

typedef __attribute__((ext_vector_type(8))) short bf16x8;   // MFMA A/B frag (4 VGPRs)
typedef __attribute__((ext_vector_type(4))) float f32x4;    // MFMA C/D frag
typedef __attribute__((ext_vector_type(2))) float f32x2;

// ---- bf16 helpers ----
__device__ __forceinline__ unsigned short f2bf(float f) {
    unsigned u = __float_as_uint(f);
    return (unsigned short)((u + 0x7FFFu + ((u >> 16) & 1u)) >> 16);
}
__device__ __forceinline__ unsigned pack2(float a, float b) {
    return (unsigned)f2bf(a) | ((unsigned)f2bf(b) << 16);
}
// ---- fp8 e4m3 helpers (HW cvt) ----
__device__ __forceinline__ unsigned pack4_fp8(float a0, float a1, float a2, float a3) {
    unsigned p = 0;
    p = __builtin_amdgcn_cvt_pk_fp8_f32(a0, a1, p, false);   // bytes 0,1
    p = __builtin_amdgcn_cvt_pk_fp8_f32(a2, a3, p, true);    // bytes 2,3
    return p;
}
__device__ __forceinline__ unsigned char f2fp8(float v) {
    unsigned p = __builtin_amdgcn_cvt_pk_fp8_f32(v, v, 0, false);
    return (unsigned char)(p & 0xFF);
}
// unpack 4 fp8 bytes -> two float2 (packed HW cvt when available)
#if __has_builtin(__builtin_amdgcn_cvt_pk_f32_fp8)
__device__ __forceinline__ f32x2 up_lo(unsigned v) { return __builtin_amdgcn_cvt_pk_f32_fp8(v, false); }
__device__ __forceinline__ f32x2 up_hi(unsigned v) { return __builtin_amdgcn_cvt_pk_f32_fp8(v, true); }
#else
__device__ __forceinline__ f32x2 up_lo(unsigned v) {
    f32x2 r; r.x = __builtin_amdgcn_cvt_f32_fp8(v, 0); r.y = __builtin_amdgcn_cvt_f32_fp8(v, 1); return r;
}
__device__ __forceinline__ f32x2 up_hi(unsigned v) {
    f32x2 r; r.x = __builtin_amdgcn_cvt_f32_fp8(v, 2); r.y = __builtin_amdgcn_cvt_f32_fp8(v, 3); return r;
}
#endif

// ---------------- prep: table->fp8, W1^T/W2^T->bf16, degree histograms ----------------
__global__ void prep_kernel(const float* __restrict__ wt, unsigned char* __restrict__ wt8,
                            const float* __restrict__ W1, unsigned short* __restrict__ W1Tb,
                            const float* __restrict__ W2, unsigned short* __restrict__ W2Tb,
                            const int* __restrict__ src0, const int* __restrict__ dst0,
                            const int* __restrict__ src1, const int* __restrict__ dst1,
                            int* cnt0, int* cnt1, int* degO0, int* degO1) {
    int i = blockIdx.x * blockDim.x + threadIdx.x;
    if (i < NSRC0 * EMB / 8) {            // 800000: pack 8 floats -> 8 fp8
        const float4* in = (const float4*)wt;
        float4 v0 = in[i * 2], v1 = in[i * 2 + 1];
        uint2 o;
        o.x = pack4_fp8(v0.x, v0.y, v0.z, v0.w);
        o.y = pack4_fp8(v1.x, v1.y, v1.z, v1.w);
        ((uint2*)wt8)[i] = o;
    }
    if (i < EMB * HID) {                  // W1[128][256] -> W1T bf16 [256][128]
        int n = i & 255, k = i >> 8;
        W1Tb[n * 128 + k] = f2bf(W1[i]);
    }
    if (i < HID * NOUT) {                 // W2[256][16] -> W2T bf16 [16][256]
        int n = i & 15, k = i >> 4;
        W2Tb[n * 256 + k] = f2bf(W2[i]);
    }
    if (i < E0) {
        atomicAdd(&cnt0[dst0[i]], 1);
        atomicAdd(&degO0[src0[i]], 1);
    }
    if (i < E1) {
        atomicAdd(&cnt1[dst1[i]], 1);
        atomicAdd(&degO1[src1[i]], 1);
    }
}

// ---------------- exclusive scan (2 blocks x 1024 threads, own dispatch) --------------
__device__ void scan_body(const int* __restrict__ cnt, int n,
                          int* __restrict__ off, int* __restrict__ cur) {
    __shared__ int sums[1024];
    int t = threadIdx.x;
    int chunk = (n + 1023) / 1024;
    int lo = t * chunk, hi = min(lo + chunk, n);
    int s = 0;
    for (int i = lo; i < hi; ++i) s += cnt[i];
    sums[t] = s;
    __syncthreads();
    for (int d = 1; d < 1024; d <<= 1) {
        int x = (t >= d) ? sums[t - d] : 0;
        __syncthreads();
        sums[t] += x;
        __syncthreads();
    }
    int run = (t == 0) ? 0 : sums[t - 1];
    for (int i = lo; i < hi; ++i) {
        off[i] = run; cur[i] = run;
        run += cnt[i];
    }
    if (t == 1023) off[n] = run;
}

__global__ void scan_kernel(const int* cnt0, int* off0, int* cur0,
                            const int* cnt1, int* off1, int* cur1) {
    if (blockIdx.x == 0) scan_body(cnt0, NDST0, off0, cur0);
    else                 scan_body(cnt1, NDST1, off1, cur1);
}

// ---------------- embed (even blocks) + edge bucket (odd blocks), interleaved ---------
// Interleave spreads bucket work across the whole dispatch (r14 appended it -> tail).
// Embed gather is POSITION-OUTER across 5 nodes: position j of a tile-sorted list maps
// to tile ~13j/50 for every node/wave/block -> statistical tile lockstep with zero
// bookkeeping (r15's explicit tile loop got the locality but drowned in overhead),
// plus 5 independent loads in flight.
__global__ void embed_bucket_kernel(const int* __restrict__ user_word,
                                    const unsigned char* __restrict__ wt8,
                                    const int* __restrict__ degO0,
                                    unsigned char* __restrict__ x0f,
                                    const int* __restrict__ src0, const int* __restrict__ dst0,
                                    const int* __restrict__ src1, const int* __restrict__ dst1,
                                    int* cur0, int* cur1, int* esrc0, int* esrc1) {
    if (blockIdx.x & 1) {                // ---- bucket part (odd blocks) ----
        int i = (blockIdx.x >> 1) * 256 + threadIdx.x;
        if (i < E0) {
            int p = atomicAdd(&cur0[dst0[i]], 1);
            esrc0[p] = src0[i];
        }
        if (i < E1) {
            int p = atomicAdd(&cur1[dst1[i]], 1);
            esrc1[p] = src1[i];
        }
        return;
    }
    // ---- embed part (even blocks) ----
    int eb = blockIdx.x >> 1;            // 0..1249
    __shared__ int raw[NPB * 50];
    __shared__ int srt[NPB * 50];
    __shared__ int cnt[NPB * 17];        // stride 17: avoids LDS bank conflicts
    int t = threadIdx.x;
    int base = eb * NPB * 50;
    for (int j = t; j < NPB * 50; j += 256)
        raw[j] = user_word[base + j];
    for (int j = t; j < NPB * 17; j += 256)
        cnt[j] = 0;
    __syncthreads();
    if (t < NPB) {                                // 1 thread sorts 1 node (in LDS)
        int* c = cnt + t * 17;
        const int* r = raw + t * 50;
        for (int j = 0; j < 50; ++j) c[r[j] >> TILE_SHIFT]++;
        int run = 0;
        for (int b = 0; b < 13; ++b) { int v = c[b]; c[b] = run; run += v; }
        int* o = srt + t * 50;
        for (int j = 0; j < 50; ++j) { int v = r[j]; o[c[v >> TILE_SHIFT]++] = v; }
    }
    __syncthreads();
    int g = t >> 5, l = t & 31;                   // 8 groups of 32 lanes
    const unsigned* wt4 = (const unsigned*)wt8;   // row = 32 uints
    // group g owns nodes g, g+8, g+16, g+24, g+32 -- processed simultaneously
    const int* id0 = srt + (g     ) * 50;
    const int* id1 = srt + (g +  8) * 50;
    const int* id2 = srt + (g + 16) * 50;
    const int* id3 = srt + (g + 24) * 50;
    const int* id4 = srt + (g + 32) * 50;
    f32x2 a01[5], a23[5];
    #pragma unroll
    for (int k = 0; k < 5; ++k) { a01[k] = (f32x2){0.f, 0.f}; a23[k] = (f32x2){0.f, 0.f}; }
    for (int j = 0; j < 50; ++j) {                // position-outer: 5 loads in flight
        unsigned v0 = wt4[id0[j] * 32 + l];
        unsigned v1 = wt4[id1[j] * 32 + l];
        unsigned v2 = wt4[id2[j] * 32 + l];
        unsigned v3 = wt4[id3[j] * 32 + l];
        unsigned v4 = wt4[id4[j] * 32 + l];
        a01[0] += up_lo(v0); a23[0] += up_hi(v0);
        a01[1] += up_lo(v1); a23[1] += up_hi(v1);
        a01[2] += up_lo(v2); a23[2] += up_hi(v2);
        a01[3] += up_lo(v3); a23[3] += up_hi(v3);
        a01[4] += up_lo(v4); a23[4] += up_hi(v4);
    }
    #pragma unroll
    for (int k = 0; k < 5; ++k) {
        int node = eb * NPB + g + k * 8;
        float s = rsqrtf(fmaxf((float)degO0[node], 1.0f)) * (0.02f * X0S); // 1/50 mean
        ((unsigned*)x0f)[node * 32 + l] =
            pack4_fp8(a01[k].x * s, a01[k].y * s, a23[k].x * s, a23[k].y * s);
    }
}

// ---------------- layer-1 gather-aggregate (fp8 in, bf16 out, 1 wave/dst) ----------
__global__ void agg1_kernel(const int* __restrict__ off0, const int* __restrict__ esrc0,
                            const unsigned char* __restrict__ x0f,
                            unsigned short* __restrict__ agg1b) {
    int d = blockIdx.x;
    int t = threadIdx.x;               // 0..63
    int half = t >> 5, l = t & 31;
    int lo = off0[d], hi = off0[d + 1];
    const unsigned* x4 = (const unsigned*)x0f;     // row = 32 uints
    f32x2 a01 = {0.f, 0.f}, a23 = {0.f, 0.f};
    for (int j = lo + half; j < hi; j += 2) {
        unsigned v = x4[esrc0[j] * 32 + l];
        a01 += up_lo(v); a23 += up_hi(v);
    }
    a01.x += __shfl_down(a01.x, 32); a01.y += __shfl_down(a01.y, 32);
    a23.x += __shfl_down(a23.x, 32); a23.y += __shfl_down(a23.y, 32);
    if (half == 0) {
        float sc = rsqrtf(fmaxf((float)(hi - lo), 1.0f)) * (1.0f / X0S);
        uint2 o; o.x = pack2(a01.x * sc, a01.y * sc); o.y = pack2(a23.x * sc, a23.y * sc);
        ((uint2*)agg1b)[d * 32 + l] = o;
    }
}

// ---------------- GEMM1 via MFMA: h1 = relu(agg1 @ W1 + b1) * rsqrt(degO1), fp8 out --
__global__ void gemm1_kernel(const unsigned short* __restrict__ agg1b,
                             const int* __restrict__ degO1,
                             const unsigned short* __restrict__ W1Tb,
                             const float* __restrict__ b1,
                             unsigned char* __restrict__ h1f) {
    __shared__ float s_out[16];
    int t = threadIdx.x;
    int row0 = blockIdx.x * 16;
    if (t < 16) s_out[t] = rsqrtf(fmaxf((float)degO1[row0 + t], 1.0f)) * H1S;
    __syncthreads();
    int w = t >> 6, lane = t & 63;
    int m = lane & 15, quad = lane >> 4;
    const unsigned short* abase = agg1b + (row0 + m) * 128 + quad * 8;
    bf16x8 afr[4];
    #pragma unroll
    for (int ks = 0; ks < 4; ++ks)
        afr[ks] = *(const bf16x8*)(abase + ks * 32);
    #pragma unroll
    for (int ct = 0; ct < 4; ++ct) {
        int gcol0 = (w * 4 + ct) * 16;
        const unsigned short* bbase = W1Tb + (gcol0 + m) * 128 + quad * 8;
        f32x4 acc = {0.f, 0.f, 0.f, 0.f};
        #pragma unroll
        for (int ks = 0; ks < 4; ++ks) {
            bf16x8 bfr = *(const bf16x8*)(bbase + ks * 32);
            acc = __builtin_amdgcn_mfma_f32_16x16x32_bf16(afr[ks], bfr, acc, 0, 0, 0);
        }
        int gcol = gcol0 + m;
        float bb = b1[gcol];
        #pragma unroll
        for (int reg = 0; reg < 4; ++reg) {
            int row = quad * 4 + reg;
            h1f[(row0 + row) * 256 + gcol] = f2fp8(fmaxf(acc[reg] + bb, 0.f) * s_out[row]);
        }
    }
}

// ---------------- layer-2 gather-aggregate (fp8 in, bf16 out, 1 wave/dst) -----------
__global__ void agg2_kernel(const int* __restrict__ off1, const int* __restrict__ esrc1,
                            const unsigned char* __restrict__ h1f,
                            unsigned short* __restrict__ agg2b) {
    int d = blockIdx.x;
    int l = threadIdx.x;               // 0..63
    int lo = off1[d], hi = off1[d + 1];
    const unsigned* h4 = (const unsigned*)h1f;     // row = 64 uints
    f32x2 a01 = {0.f, 0.f}, a23 = {0.f, 0.f};
    int j = lo;
    for (; j + 1 < hi; j += 2) {
        unsigned v0 = h4[esrc1[j] * 64 + l];
        unsigned v1 = h4[esrc1[j + 1] * 64 + l];
        a01 += up_lo(v0) + up_lo(v1);
        a23 += up_hi(v0) + up_hi(v1);
    }
    if (j < hi) {
        unsigned v = h4[esrc1[j] * 64 + l];
        a01 += up_lo(v); a23 += up_hi(v);
    }
    float sc = rsqrtf(fmaxf((float)(hi - lo), 1.0f)) * (1.0f / H1S);
    uint2 o; o.x = pack2(a01.x * sc, a01.y * sc); o.y = pack2(a23.x * sc, a23.y * sc);
    ((uint2*)agg2b)[d * 64 + l] = o;
}

// ---------------- GEMM2 via MFMA: out = relu(agg2 @ W2 + b2) (+ labels) --------------
__global__ void gemm2_kernel(const unsigned short* __restrict__ agg2b,
                             const unsigned short* __restrict__ W2Tb,
                             const float* __restrict__ b2,
                             const int* __restrict__ labels,
                             float* __restrict__ out) {
    int lane = threadIdx.x;            // 0..63
    int row0 = blockIdx.x * 16;
    int m = lane & 15, quad = lane >> 4;
    int arow = min(row0 + m, NDST1 - 1);           // clamp OOB reads (last block)
    const unsigned short* abase = agg2b + arow * 256 + quad * 8;
    const unsigned short* bbase = W2Tb + m * 256 + quad * 8;
    f32x4 acc = {0.f, 0.f, 0.f, 0.f};
    #pragma unroll
    for (int ks = 0; ks < 8; ++ks) {
        bf16x8 af = *(const bf16x8*)(abase + ks * 32);
        bf16x8 bf = *(const bf16x8*)(bbase + ks * 32);
        acc = __builtin_amdgcn_mfma_f32_16x16x32_bf16(af, bf, acc, 0, 0, 0);
    }
    float bb = b2[m];
    #pragma unroll
    for (int reg = 0; reg < 4; ++reg) {
        int row = row0 + quad * 4 + reg;
        if (row < NDST1)
            out[row * NOUT + m] = fmaxf(acc[reg] + bb, 0.f);
    }
    if (lane < 16 && row0 + lane < NDST1)
        out[NDST1 * NOUT + row0 + lane] = (float)labels[row0 + lane];
}

extern "C" void kernel_launch(void* const* d_in, const int* in_sizes, int n_in,
                              void* d_out, int out_size, void* d_ws, size_t ws_size,
                              hipStream_t stream) {
    const int*   user_word  = (const int*)d_in[0];
    const int*   labels     = (const int*)d_in[1];
    const int*   src0       = (const int*)d_in[2];
    const int*   dst0       = (const int*)d_in[3];
    const int*   src1       = (const int*)d_in[4];
    const int*   dst1       = (const int*)d_in[5];
    const float* word_table = (const float*)d_in[6];
    const float* W1         = (const float*)d_in[7];
    const float* b1         = (const float*)d_in[8];
    const float* W2         = (const float*)d_in[9];
    const float* b2         = (const float*)d_in[10];

    int* iws = (int*)d_ws;
    int* cnt0  = iws;            // 20000  ┐
    int* cnt1  = iws + 20000;    //  5000  │ zeroed (95000 ints)
    int* degO0 = iws + 25000;    // 50000  │
    int* degO1 = iws + 75000;    // 20000  ┘
    int* off0  = iws + 95000;    // 20001
    int* off1  = iws + 115001;   //  5001
    int* cur0  = iws + 120002;   // 20000
    int* cur1  = iws + 140002;   //  5000
    int* esrc0 = iws + 145002;   // 300000
    int* esrc1 = iws + 445002;   // 75000   (end 520002; pad to 520004)
    unsigned char*  wt8   = (unsigned char*)(iws + 520004);   // 6.4M fp8  = 1.6M ints
    unsigned char*  x0f   = (unsigned char*)(iws + 2120004);  // 6.4M fp8  = 1.6M ints
    unsigned char*  h1f   = (unsigned char*)(iws + 3720004);  // 5.12M fp8 = 1.28M ints
    unsigned short* agg1b = (unsigned short*)(iws + 5000004); // 2.56M bf16 = 1.28M ints
    unsigned short* agg2b = (unsigned short*)(iws + 6280004); // 1.28M bf16 = 640K ints
    unsigned short* W1Tb  = (unsigned short*)(iws + 6920004); // 32768 bf16
    unsigned short* W2Tb  = (unsigned short*)(iws + 6936388); // 4096 bf16 (end ≈ 27.8 MB)

    hipMemsetAsync(iws, 0, 95000 * sizeof(int), stream);

    prep_kernel<<<(NSRC0 * EMB / 8 + 255) / 256, 256, 0, stream>>>(
        word_table, wt8, W1, W1Tb, W2, W2Tb,
        src0, dst0, src1, dst1, cnt0, cnt1, degO0, degO1);
    scan_kernel<<<2, 1024, 0, stream>>>(cnt0, off0, cur0, cnt1, off1, cur1);
    embed_bucket_kernel<<<NEMB_BLK * 2, 256, 0, stream>>>(
        user_word, wt8, degO0, x0f,
        src0, dst0, src1, dst1, cur0, cur1, esrc0, esrc1);
    agg1_kernel<<<NDST0, 64, 0, stream>>>(off0, esrc0, x0f, agg1b);
    gemm1_kernel<<<NDST0 / 16, 256, 0, stream>>>(agg1b, degO1, W1Tb, b1, h1f);
    agg2_kernel<<<NDST1, 64, 0, stream>>>(off1, esrc1, h1f, agg2b);
    gemm2_kernel<<<(NDST1 + 15) / 16, 64, 0, stream>>>(agg2b, W2Tb, b2, labels, (float*)d_out);
}

// Round 17
// 263.209 us; speedup vs baseline: 1.1980x; 1.0198x over previous
//
#include <hip/hip_runtime.h>

#define E0     300000
#define E1     75000
#define NSRC0  50000
#define NDST0  20000
#define NDST1  5000
#define EMB    128
#define HID    256
#define NOUT   16

#define NPB        40     // nodes per embed block (1250 * 40 = 50000 exactly)
#define TILE_SHIFT 12     // 4096-row vocab tiles; tiles 0..12
#define NEMB_BLK   (NSRC0 / NPB)          // 1250

#define X0S  32.0f        // fp8 pre-scale for x0  (undone in agg1)
#define H1S  64.0f        // fp8 pre-scale for h1  (undone in agg2)

typedef __attribute__((ext_vector_type(8))) short bf16x8;   // MFMA A/B frag (4 VGPRs)
typedef __attribute__((ext_vector_type(4))) float f32x4;    // MFMA C/D frag
typedef __attribute__((ext_vector_type(2))) float f32x2;

// ---- bf16 helpers ----
__device__ __forceinline__ unsigned short f2bf(float f) {
    unsigned u = __float_as_uint(f);
    return (unsigned short)((u + 0x7FFFu + ((u >> 16) & 1u)) >> 16);
}
__device__ __forceinline__ unsigned pack2(float a, float b) {
    return (unsigned)f2bf(a) | ((unsigned)f2bf(b) << 16);
}
// ---- fp8 e4m3 helpers (HW cvt) ----
__device__ __forceinline__ unsigned pack4_fp8(float a0, float a1, float a2, float a3) {
    unsigned p = 0;
    p = __builtin_amdgcn_cvt_pk_fp8_f32(a0, a1, p, false);   // bytes 0,1
    p = __builtin_amdgcn_cvt_pk_fp8_f32(a2, a3, p, true);    // bytes 2,3
    return p;
}
__device__ __forceinline__ unsigned char f2fp8(float v) {
    unsigned p = __builtin_amdgcn_cvt_pk_fp8_f32(v, v, 0, false);
    return (unsigned char)(p & 0xFF);
}
// unpack 4 fp8 bytes -> two float2 (packed HW cvt when available)
#if __has_builtin(__builtin_amdgcn_cvt_pk_f32_fp8)
__device__ __forceinline__ f32x2 up_lo(unsigned v) { return __builtin_amdgcn_cvt_pk_f32_fp8(v, false); }
__device__ __forceinline__ f32x2 up_hi(unsigned v) { return __builtin_amdgcn_cvt_pk_f32_fp8(v, true); }
#else
__device__ __forceinline__ f32x2 up_lo(unsigned v) {
    f32x2 r; r.x = __builtin_amdgcn_cvt_f32_fp8(v, 0); r.y = __builtin_amdgcn_cvt_f32_fp8(v, 1); return r;
}
__device__ __forceinline__ f32x2 up_hi(unsigned v) {
    f32x2 r; r.x = __builtin_amdgcn_cvt_f32_fp8(v, 2); r.y = __builtin_amdgcn_cvt_f32_fp8(v, 3); return r;
}
#endif

// ---------------- prep: table->fp8, W1^T/W2^T->bf16, degree histograms ----------------
__global__ void prep_kernel(const float* __restrict__ wt, unsigned char* __restrict__ wt8,
                            const float* __restrict__ W1, unsigned short* __restrict__ W1Tb,
                            const float* __restrict__ W2, unsigned short* __restrict__ W2Tb,
                            const int* __restrict__ src0, const int* __restrict__ dst0,
                            const int* __restrict__ src1, const int* __restrict__ dst1,
                            int* cnt0, int* cnt1, int* degO0, int* degO1) {
    int i = blockIdx.x * blockDim.x + threadIdx.x;
    if (i < NSRC0 * EMB / 8) {            // 800000: pack 8 floats -> 8 fp8
        const float4* in = (const float4*)wt;
        float4 v0 = in[i * 2], v1 = in[i * 2 + 1];
        uint2 o;
        o.x = pack4_fp8(v0.x, v0.y, v0.z, v0.w);
        o.y = pack4_fp8(v1.x, v1.y, v1.z, v1.w);
        ((uint2*)wt8)[i] = o;
    }
    if (i < EMB * HID) {                  // W1[128][256] -> W1T bf16 [256][128]
        int n = i & 255, k = i >> 8;
        W1Tb[n * 128 + k] = f2bf(W1[i]);
    }
    if (i < HID * NOUT) {                 // W2[256][16] -> W2T bf16 [16][256]
        int n = i & 15, k = i >> 4;
        W2Tb[n * 256 + k] = f2bf(W2[i]);
    }
    if (i < E0) {
        atomicAdd(&cnt0[dst0[i]], 1);
        atomicAdd(&degO0[src0[i]], 1);
    }
    if (i < E1) {
        atomicAdd(&cnt1[dst1[i]], 1);
        atomicAdd(&degO1[src1[i]], 1);
    }
}

// ---------------- exclusive scan (2 blocks x 1024 threads, own dispatch) --------------
__device__ void scan_body(const int* __restrict__ cnt, int n,
                          int* __restrict__ off, int* __restrict__ cur) {
    __shared__ int sums[1024];
    int t = threadIdx.x;
    int chunk = (n + 1023) / 1024;
    int lo = t * chunk, hi = min(lo + chunk, n);
    int s = 0;
    for (int i = lo; i < hi; ++i) s += cnt[i];
    sums[t] = s;
    __syncthreads();
    for (int d = 1; d < 1024; d <<= 1) {
        int x = (t >= d) ? sums[t - d] : 0;
        __syncthreads();
        sums[t] += x;
        __syncthreads();
    }
    int run = (t == 0) ? 0 : sums[t - 1];
    for (int i = lo; i < hi; ++i) {
        off[i] = run; cur[i] = run;
        run += cnt[i];
    }
    if (t == 1023) off[n] = run;
}

__global__ void scan_kernel(const int* cnt0, int* off0, int* cur0,
                            const int* cnt1, int* off1, int* cur1) {
    if (blockIdx.x == 0) scan_body(cnt0, NDST0, off0, cur0);
    else                 scan_body(cnt1, NDST1, off1, cur1);
}

// ---------------- embed (even blocks) + edge bucket (odd blocks), interleaved ---------
// Position-outer gather over 5 nodes, j unrolled x2 -> 10 independent loads in flight.
// Adjacent j = adjacent tile quantiles, so working set unchanged (no r11-style thrash).
__global__ void embed_bucket_kernel(const int* __restrict__ user_word,
                                    const unsigned char* __restrict__ wt8,
                                    const int* __restrict__ degO0,
                                    unsigned char* __restrict__ x0f,
                                    const int* __restrict__ src0, const int* __restrict__ dst0,
                                    const int* __restrict__ src1, const int* __restrict__ dst1,
                                    int* cur0, int* cur1, int* esrc0, int* esrc1) {
    if (blockIdx.x & 1) {                // ---- bucket part (odd blocks) ----
        int i = (blockIdx.x >> 1) * 256 + threadIdx.x;
        if (i < E0) {
            int p = atomicAdd(&cur0[dst0[i]], 1);
            esrc0[p] = src0[i];
        }
        if (i < E1) {
            int p = atomicAdd(&cur1[dst1[i]], 1);
            esrc1[p] = src1[i];
        }
        return;
    }
    // ---- embed part (even blocks) ----
    int eb = blockIdx.x >> 1;            // 0..1249
    __shared__ int raw[NPB * 50];
    __shared__ int srt[NPB * 50];
    __shared__ int cnt[NPB * 17];        // stride 17: avoids LDS bank conflicts
    int t = threadIdx.x;
    int base = eb * NPB * 50;
    for (int j = t; j < NPB * 50; j += 256)
        raw[j] = user_word[base + j];
    for (int j = t; j < NPB * 17; j += 256)
        cnt[j] = 0;
    __syncthreads();
    if (t < NPB) {                                // 1 thread sorts 1 node (in LDS)
        int* c = cnt + t * 17;
        const int* r = raw + t * 50;
        for (int j = 0; j < 50; ++j) c[r[j] >> TILE_SHIFT]++;
        int run = 0;
        for (int b = 0; b < 13; ++b) { int v = c[b]; c[b] = run; run += v; }
        int* o = srt + t * 50;
        for (int j = 0; j < 50; ++j) { int v = r[j]; o[c[v >> TILE_SHIFT]++] = v; }
    }
    __syncthreads();
    int g = t >> 5, l = t & 31;                   // 8 groups of 32 lanes
    const unsigned* wt4 = (const unsigned*)wt8;   // row = 32 uints
    const int* id0 = srt + (g     ) * 50;
    const int* id1 = srt + (g +  8) * 50;
    const int* id2 = srt + (g + 16) * 50;
    const int* id3 = srt + (g + 24) * 50;
    const int* id4 = srt + (g + 32) * 50;
    f32x2 a01[5], a23[5];
    #pragma unroll
    for (int k = 0; k < 5; ++k) { a01[k] = (f32x2){0.f, 0.f}; a23[k] = (f32x2){0.f, 0.f}; }
    for (int j = 0; j < 50; j += 2) {             // 2 positions x 5 nodes = 10 in flight
        unsigned v0a = wt4[id0[j] * 32 + l], v0b = wt4[id0[j + 1] * 32 + l];
        unsigned v1a = wt4[id1[j] * 32 + l], v1b = wt4[id1[j + 1] * 32 + l];
        unsigned v2a = wt4[id2[j] * 32 + l], v2b = wt4[id2[j + 1] * 32 + l];
        unsigned v3a = wt4[id3[j] * 32 + l], v3b = wt4[id3[j + 1] * 32 + l];
        unsigned v4a = wt4[id4[j] * 32 + l], v4b = wt4[id4[j + 1] * 32 + l];
        a01[0] += up_lo(v0a) + up_lo(v0b); a23[0] += up_hi(v0a) + up_hi(v0b);
        a01[1] += up_lo(v1a) + up_lo(v1b); a23[1] += up_hi(v1a) + up_hi(v1b);
        a01[2] += up_lo(v2a) + up_lo(v2b); a23[2] += up_hi(v2a) + up_hi(v2b);
        a01[3] += up_lo(v3a) + up_lo(v3b); a23[3] += up_hi(v3a) + up_hi(v3b);
        a01[4] += up_lo(v4a) + up_lo(v4b); a23[4] += up_hi(v4a) + up_hi(v4b);
    }
    #pragma unroll
    for (int k = 0; k < 5; ++k) {
        int node = eb * NPB + g + k * 8;
        float s = rsqrtf(fmaxf((float)degO0[node], 1.0f)) * (0.02f * X0S); // 1/50 mean
        ((unsigned*)x0f)[node * 32 + l] =
            pack4_fp8(a01[k].x * s, a01[k].y * s, a23[k].x * s, a23[k].y * s);
    }
}

// ---------------- layer-1 gather-aggregate (fp8 in, bf16 out, 1 wave/dst, 4-deep) ----
__global__ void agg1_kernel(const int* __restrict__ off0, const int* __restrict__ esrc0,
                            const unsigned char* __restrict__ x0f,
                            unsigned short* __restrict__ agg1b) {
    int d = blockIdx.x;
    int t = threadIdx.x;               // 0..63
    int half = t >> 5, l = t & 31;
    int lo = off0[d], hi = off0[d + 1];
    const unsigned* x4 = (const unsigned*)x0f;     // row = 32 uints
    f32x2 a01a = {0.f, 0.f}, a23a = {0.f, 0.f};
    f32x2 a01b = {0.f, 0.f}, a23b = {0.f, 0.f};
    int j = lo + half;
    for (; j + 2 < hi; j += 4) {                   // 2 per half -> 4 in flight/wave
        unsigned va = x4[esrc0[j] * 32 + l];
        unsigned vb = x4[esrc0[j + 2] * 32 + l];
        a01a += up_lo(va); a23a += up_hi(va);
        a01b += up_lo(vb); a23b += up_hi(vb);
    }
    if (j < hi) {
        unsigned v = x4[esrc0[j] * 32 + l];
        a01a += up_lo(v); a23a += up_hi(v);
    }
    f32x2 a01 = a01a + a01b, a23 = a23a + a23b;
    a01.x += __shfl_down(a01.x, 32); a01.y += __shfl_down(a01.y, 32);
    a23.x += __shfl_down(a23.x, 32); a23.y += __shfl_down(a23.y, 32);
    if (half == 0) {
        float sc = rsqrtf(fmaxf((float)(hi - lo), 1.0f)) * (1.0f / X0S);
        uint2 o; o.x = pack2(a01.x * sc, a01.y * sc); o.y = pack2(a23.x * sc, a23.y * sc);
        ((uint2*)agg1b)[d * 32 + l] = o;
    }
}

// ---------------- GEMM1 via MFMA: h1 = relu(agg1 @ W1 + b1) * rsqrt(degO1), fp8 out --
__global__ void gemm1_kernel(const unsigned short* __restrict__ agg1b,
                             const int* __restrict__ degO1,
                             const unsigned short* __restrict__ W1Tb,
                             const float* __restrict__ b1,
                             unsigned char* __restrict__ h1f) {
    __shared__ float s_out[16];
    int t = threadIdx.x;
    int row0 = blockIdx.x * 16;
    if (t < 16) s_out[t] = rsqrtf(fmaxf((float)degO1[row0 + t], 1.0f)) * H1S;
    __syncthreads();
    int w = t >> 6, lane = t & 63;
    int m = lane & 15, quad = lane >> 4;
    const unsigned short* abase = agg1b + (row0 + m) * 128 + quad * 8;
    bf16x8 afr[4];
    #pragma unroll
    for (int ks = 0; ks < 4; ++ks)
        afr[ks] = *(const bf16x8*)(abase + ks * 32);
    #pragma unroll
    for (int ct = 0; ct < 4; ++ct) {
        int gcol0 = (w * 4 + ct) * 16;
        const unsigned short* bbase = W1Tb + (gcol0 + m) * 128 + quad * 8;
        f32x4 acc = {0.f, 0.f, 0.f, 0.f};
        #pragma unroll
        for (int ks = 0; ks < 4; ++ks) {
            bf16x8 bfr = *(const bf16x8*)(bbase + ks * 32);
            acc = __builtin_amdgcn_mfma_f32_16x16x32_bf16(afr[ks], bfr, acc, 0, 0, 0);
        }
        int gcol = gcol0 + m;
        float bb = b1[gcol];
        #pragma unroll
        for (int reg = 0; reg < 4; ++reg) {
            int row = quad * 4 + reg;
            h1f[(row0 + row) * 256 + gcol] = f2fp8(fmaxf(acc[reg] + bb, 0.f) * s_out[row]);
        }
    }
}

// ---------------- layer-2 gather-aggregate (fp8 in, bf16 out, 1 wave/dst, 4-deep) ----
__global__ void agg2_kernel(const int* __restrict__ off1, const int* __restrict__ esrc1,
                            const unsigned char* __restrict__ h1f,
                            unsigned short* __restrict__ agg2b) {
    int d = blockIdx.x;
    int l = threadIdx.x;               // 0..63
    int lo = off1[d], hi = off1[d + 1];
    const unsigned* h4 = (const unsigned*)h1f;     // row = 64 uints
    f32x2 a01 = {0.f, 0.f}, a23 = {0.f, 0.f};
    int j = lo;
    for (; j + 3 < hi; j += 4) {                   // 4 loads in flight
        unsigned v0 = h4[esrc1[j] * 64 + l];
        unsigned v1 = h4[esrc1[j + 1] * 64 + l];
        unsigned v2 = h4[esrc1[j + 2] * 64 + l];
        unsigned v3 = h4[esrc1[j + 3] * 64 + l];
        a01 += up_lo(v0) + up_lo(v1) + up_lo(v2) + up_lo(v3);
        a23 += up_hi(v0) + up_hi(v1) + up_hi(v2) + up_hi(v3);
    }
    for (; j < hi; ++j) {
        unsigned v = h4[esrc1[j] * 64 + l];
        a01 += up_lo(v); a23 += up_hi(v);
    }
    float sc = rsqrtf(fmaxf((float)(hi - lo), 1.0f)) * (1.0f / H1S);
    uint2 o; o.x = pack2(a01.x * sc, a01.y * sc); o.y = pack2(a23.x * sc, a23.y * sc);
    ((uint2*)agg2b)[d * 64 + l] = o;
}

// ---------------- GEMM2 via MFMA: out = relu(agg2 @ W2 + b2) (+ labels) --------------
__global__ void gemm2_kernel(const unsigned short* __restrict__ agg2b,
                             const unsigned short* __restrict__ W2Tb,
                             const float* __restrict__ b2,
                             const int* __restrict__ labels,
                             float* __restrict__ out) {
    int lane = threadIdx.x;            // 0..63
    int row0 = blockIdx.x * 16;
    int m = lane & 15, quad = lane >> 4;
    int arow = min(row0 + m, NDST1 - 1);           // clamp OOB reads (last block)
    const unsigned short* abase = agg2b + arow * 256 + quad * 8;
    const unsigned short* bbase = W2Tb + m * 256 + quad * 8;
    f32x4 acc = {0.f, 0.f, 0.f, 0.f};
    #pragma unroll
    for (int ks = 0; ks < 8; ++ks) {
        bf16x8 af = *(const bf16x8*)(abase + ks * 32);
        bf16x8 bf = *(const bf16x8*)(bbase + ks * 32);
        acc = __builtin_amdgcn_mfma_f32_16x16x32_bf16(af, bf, acc, 0, 0, 0);
    }
    float bb = b2[m];
    #pragma unroll
    for (int reg = 0; reg < 4; ++reg) {
        int row = row0 + quad * 4 + reg;
        if (row < NDST1)
            out[row * NOUT + m] = fmaxf(acc[reg] + bb, 0.f);
    }
    if (lane < 16 && row0 + lane < NDST1)
        out[NDST1 * NOUT + row0 + lane] = (float)labels[row0 + lane];
}

extern "C" void kernel_launch(void* const* d_in, const int* in_sizes, int n_in,
                              void* d_out, int out_size, void* d_ws, size_t ws_size,
                              hipStream_t stream) {
    const int*   user_word  = (const int*)d_in[0];
    const int*   labels     = (const int*)d_in[1];
    const int*   src0       = (const int*)d_in[2];
    const int*   dst0       = (const int*)d_in[3];
    const int*   src1       = (const int*)d_in[4];
    const int*   dst1       = (const int*)d_in[5];
    const float* word_table = (const float*)d_in[6];
    const float* W1         = (const float*)d_in[7];
    const float* b1         = (const float*)d_in[8];
    const float* W2         = (const float*)d_in[9];
    const float* b2         = (const float*)d_in[10];

    int* iws = (int*)d_ws;
    int* cnt0  = iws;            // 20000  ┐
    int* cnt1  = iws + 20000;    //  5000  │ zeroed (95000 ints)
    int* degO0 = iws + 25000;    // 50000  │
    int* degO1 = iws + 75000;    // 20000  ┘
    int* off0  = iws + 95000;    // 20001
    int* off1  = iws + 115001;   //  5001
    int* cur0  = iws + 120002;   // 20000
    int* cur1  = iws + 140002;   //  5000
    int* esrc0 = iws + 145002;   // 300000
    int* esrc1 = iws + 445002;   // 75000   (end 520002; pad to 520004)
    unsigned char*  wt8   = (unsigned char*)(iws + 520004);   // 6.4M fp8  = 1.6M ints
    unsigned char*  x0f   = (unsigned char*)(iws + 2120004);  // 6.4M fp8  = 1.6M ints
    unsigned char*  h1f   = (unsigned char*)(iws + 3720004);  // 5.12M fp8 = 1.28M ints
    unsigned short* agg1b = (unsigned short*)(iws + 5000004); // 2.56M bf16 = 1.28M ints
    unsigned short* agg2b = (unsigned short*)(iws + 6280004); // 1.28M bf16 = 640K ints
    unsigned short* W1Tb  = (unsigned short*)(iws + 6920004); // 32768 bf16
    unsigned short* W2Tb  = (unsigned short*)(iws + 6936388); // 4096 bf16 (end ≈ 27.8 MB)

    hipMemsetAsync(iws, 0, 95000 * sizeof(int), stream);

    prep_kernel<<<(NSRC0 * EMB / 8 + 255) / 256, 256, 0, stream>>>(
        word_table, wt8, W1, W1Tb, W2, W2Tb,
        src0, dst0, src1, dst1, cnt0, cnt1, degO0, degO1);
    scan_kernel<<<2, 1024, 0, stream>>>(cnt0, off0, cur0, cnt1, off1, cur1);
    embed_bucket_kernel<<<NEMB_BLK * 2, 256, 0, stream>>>(
        user_word, wt8, degO0, x0f,
        src0, dst0, src1, dst1, cur0, cur1, esrc0, esrc1);
    agg1_kernel<<<NDST0, 64, 0, stream>>>(off0, esrc0, x0f, agg1b);
    gemm1_kernel<<<NDST0 / 16, 256, 0, stream>>>(agg1b, degO1, W1Tb, b1, h1f);
    agg2_kernel<<<NDST1, 64, 0, stream>>>(off1, esrc1, h1f, agg2b);
    gemm2_kernel<<<(NDST1 + 15) / 16, 64, 0, stream>>>(agg2b, W2Tb, b2, labels, (float*)d_out);
}

// Round 18
// 258.582 us; speedup vs baseline: 1.2195x; 1.0179x over previous
//
#include <hip/hip_runtime.h>

#define E0     300000
#define E1     75000
#define NSRC0  50000
#define NDST0  20000
#define NDST1  5000
#define EMB    128
#define HID    256
#define NOUT   16

#define NPB        40     // nodes per embed block (1250 * 40 = 50000 exactly)
#define TILE_SHIFT 12     // 4096-row vocab tiles; tiles 0..12
#define NEMB_BLK   (NSRC0 / NPB)          // 1250

#define X0S  32.0f        // fp8 pre-scale for x0  (undone in layer1 agg)
#define H1S  64.0f        // fp8 pre-scale for h1  (undone in layer2 agg)

typedef __attribute__((ext_vector_type(8))) short bf16x8;   // MFMA A/B frag (4 VGPRs)
typedef __attribute__((ext_vector_type(4))) float f32x4;    // MFMA C/D frag
typedef __attribute__((ext_vector_type(2))) float f32x2;

// ---- bf16 helpers ----
__device__ __forceinline__ unsigned short f2bf(float f) {
    unsigned u = __float_as_uint(f);
    return (unsigned short)((u + 0x7FFFu + ((u >> 16) & 1u)) >> 16);
}
__device__ __forceinline__ unsigned pack2(float a, float b) {
    return (unsigned)f2bf(a) | ((unsigned)f2bf(b) << 16);
}
// ---- fp8 e4m3 helpers (HW cvt) ----
__device__ __forceinline__ unsigned pack4_fp8(float a0, float a1, float a2, float a3) {
    unsigned p = 0;
    p = __builtin_amdgcn_cvt_pk_fp8_f32(a0, a1, p, false);   // bytes 0,1
    p = __builtin_amdgcn_cvt_pk_fp8_f32(a2, a3, p, true);    // bytes 2,3
    return p;
}
__device__ __forceinline__ unsigned char f2fp8(float v) {
    unsigned p = __builtin_amdgcn_cvt_pk_fp8_f32(v, v, 0, false);
    return (unsigned char)(p & 0xFF);
}
// unpack 4 fp8 bytes -> two float2 (packed HW cvt when available)
#if __has_builtin(__builtin_amdgcn_cvt_pk_f32_fp8)
__device__ __forceinline__ f32x2 up_lo(unsigned v) { return __builtin_amdgcn_cvt_pk_f32_fp8(v, false); }
__device__ __forceinline__ f32x2 up_hi(unsigned v) { return __builtin_amdgcn_cvt_pk_f32_fp8(v, true); }
#else
__device__ __forceinline__ f32x2 up_lo(unsigned v) {
    f32x2 r; r.x = __builtin_amdgcn_cvt_f32_fp8(v, 0); r.y = __builtin_amdgcn_cvt_f32_fp8(v, 1); return r;
}
__device__ __forceinline__ f32x2 up_hi(unsigned v) {
    f32x2 r; r.x = __builtin_amdgcn_cvt_f32_fp8(v, 2); r.y = __builtin_amdgcn_cvt_f32_fp8(v, 3); return r;
}
#endif

// ---------------- prep: table->fp8, W1^T/W2^T->bf16, degree histograms ----------------
__global__ void prep_kernel(const float* __restrict__ wt, unsigned char* __restrict__ wt8,
                            const float* __restrict__ W1, unsigned short* __restrict__ W1Tb,
                            const float* __restrict__ W2, unsigned short* __restrict__ W2Tb,
                            const int* __restrict__ src0, const int* __restrict__ dst0,
                            const int* __restrict__ src1, const int* __restrict__ dst1,
                            int* cnt0, int* cnt1, int* degO0, int* degO1) {
    int i = blockIdx.x * blockDim.x + threadIdx.x;
    if (i < NSRC0 * EMB / 8) {            // 800000: pack 8 floats -> 8 fp8
        const float4* in = (const float4*)wt;
        float4 v0 = in[i * 2], v1 = in[i * 2 + 1];
        uint2 o;
        o.x = pack4_fp8(v0.x, v0.y, v0.z, v0.w);
        o.y = pack4_fp8(v1.x, v1.y, v1.z, v1.w);
        ((uint2*)wt8)[i] = o;
    }
    if (i < EMB * HID) {                  // W1[128][256] -> W1T bf16 [256][128]
        int n = i & 255, k = i >> 8;
        W1Tb[n * 128 + k] = f2bf(W1[i]);
    }
    if (i < HID * NOUT) {                 // W2[256][16] -> W2T bf16 [16][256]
        int n = i & 15, k = i >> 4;
        W2Tb[n * 256 + k] = f2bf(W2[i]);
    }
    if (i < E0) {
        atomicAdd(&cnt0[dst0[i]], 1);
        atomicAdd(&degO0[src0[i]], 1);
    }
    if (i < E1) {
        atomicAdd(&cnt1[dst1[i]], 1);
        atomicAdd(&degO1[src1[i]], 1);
    }
}

// ---------------- exclusive scan (2 blocks x 1024 threads, own dispatch) --------------
__device__ void scan_body(const int* __restrict__ cnt, int n,
                          int* __restrict__ off, int* __restrict__ cur) {
    __shared__ int sums[1024];
    int t = threadIdx.x;
    int chunk = (n + 1023) / 1024;
    int lo = t * chunk, hi = min(lo + chunk, n);
    int s = 0;
    for (int i = lo; i < hi; ++i) s += cnt[i];
    sums[t] = s;
    __syncthreads();
    for (int d = 1; d < 1024; d <<= 1) {
        int x = (t >= d) ? sums[t - d] : 0;
        __syncthreads();
        sums[t] += x;
        __syncthreads();
    }
    int run = (t == 0) ? 0 : sums[t - 1];
    for (int i = lo; i < hi; ++i) {
        off[i] = run; cur[i] = run;
        run += cnt[i];
    }
    if (t == 1023) off[n] = run;
}

__global__ void scan_kernel(const int* cnt0, int* off0, int* cur0,
                            const int* cnt1, int* off1, int* cur1) {
    if (blockIdx.x == 0) scan_body(cnt0, NDST0, off0, cur0);
    else                 scan_body(cnt1, NDST1, off1, cur1);
}

// ---------------- embed (even blocks) + edge bucket (odd blocks), interleaved ---------
// Position-outer gather over 5 tile-sorted nodes -> statistical tile lockstep (r16).
__global__ void embed_bucket_kernel(const int* __restrict__ user_word,
                                    const unsigned char* __restrict__ wt8,
                                    const int* __restrict__ degO0,
                                    unsigned char* __restrict__ x0f,
                                    const int* __restrict__ src0, const int* __restrict__ dst0,
                                    const int* __restrict__ src1, const int* __restrict__ dst1,
                                    int* cur0, int* cur1, int* esrc0, int* esrc1) {
    if (blockIdx.x & 1) {                // ---- bucket part (odd blocks) ----
        int i = (blockIdx.x >> 1) * 256 + threadIdx.x;
        if (i < E0) {
            int p = atomicAdd(&cur0[dst0[i]], 1);
            esrc0[p] = src0[i];
        }
        if (i < E1) {
            int p = atomicAdd(&cur1[dst1[i]], 1);
            esrc1[p] = src1[i];
        }
        return;
    }
    // ---- embed part (even blocks) ----
    int eb = blockIdx.x >> 1;            // 0..1249
    __shared__ int raw[NPB * 50];
    __shared__ int srt[NPB * 50];
    __shared__ int cnt[NPB * 17];        // stride 17: avoids LDS bank conflicts
    int t = threadIdx.x;
    int base = eb * NPB * 50;
    for (int j = t; j < NPB * 50; j += 256)
        raw[j] = user_word[base + j];
    for (int j = t; j < NPB * 17; j += 256)
        cnt[j] = 0;
    __syncthreads();
    if (t < NPB) {                                // 1 thread sorts 1 node (in LDS)
        int* c = cnt + t * 17;
        const int* r = raw + t * 50;
        for (int j = 0; j < 50; ++j) c[r[j] >> TILE_SHIFT]++;
        int run = 0;
        for (int b = 0; b < 13; ++b) { int v = c[b]; c[b] = run; run += v; }
        int* o = srt + t * 50;
        for (int j = 0; j < 50; ++j) { int v = r[j]; o[c[v >> TILE_SHIFT]++] = v; }
    }
    __syncthreads();
    int g = t >> 5, l = t & 31;                   // 8 groups of 32 lanes
    const unsigned* wt4 = (const unsigned*)wt8;   // row = 32 uints
    const int* id0 = srt + (g     ) * 50;
    const int* id1 = srt + (g +  8) * 50;
    const int* id2 = srt + (g + 16) * 50;
    const int* id3 = srt + (g + 24) * 50;
    const int* id4 = srt + (g + 32) * 50;
    f32x2 a01[5], a23[5];
    #pragma unroll
    for (int k = 0; k < 5; ++k) { a01[k] = (f32x2){0.f, 0.f}; a23[k] = (f32x2){0.f, 0.f}; }
    for (int j = 0; j < 50; j += 2) {             // 2 positions x 5 nodes in flight
        unsigned v0a = wt4[id0[j] * 32 + l], v0b = wt4[id0[j + 1] * 32 + l];
        unsigned v1a = wt4[id1[j] * 32 + l], v1b = wt4[id1[j + 1] * 32 + l];
        unsigned v2a = wt4[id2[j] * 32 + l], v2b = wt4[id2[j + 1] * 32 + l];
        unsigned v3a = wt4[id3[j] * 32 + l], v3b = wt4[id3[j + 1] * 32 + l];
        unsigned v4a = wt4[id4[j] * 32 + l], v4b = wt4[id4[j + 1] * 32 + l];
        a01[0] += up_lo(v0a) + up_lo(v0b); a23[0] += up_hi(v0a) + up_hi(v0b);
        a01[1] += up_lo(v1a) + up_lo(v1b); a23[1] += up_hi(v1a) + up_hi(v1b);
        a01[2] += up_lo(v2a) + up_lo(v2b); a23[2] += up_hi(v2a) + up_hi(v2b);
        a01[3] += up_lo(v3a) + up_lo(v3b); a23[3] += up_hi(v3a) + up_hi(v3b);
        a01[4] += up_lo(v4a) + up_lo(v4b); a23[4] += up_hi(v4a) + up_hi(v4b);
    }
    #pragma unroll
    for (int k = 0; k < 5; ++k) {
        int node = eb * NPB + g + k * 8;
        float s = rsqrtf(fmaxf((float)degO0[node], 1.0f)) * (0.02f * X0S); // 1/50 mean
        ((unsigned*)x0f)[node * 32 + l] =
            pack4_fp8(a01[k].x * s, a01[k].y * s, a23[k].x * s, a23[k].y * s);
    }
}

// ---------------- layer1: agg (16 waves, 1 dst/wave) + MFMA GEMM, fused --------------
// 1024 threads = 16 waves; wave w aggregates dst row0+w (full TLP: 20000 waves total,
// same as standalone agg1 -- r8's failure was 4 waves x 4 serial rows). LDS A-tile
// [16][136] bf16 (pad 8 -> b128 reads are 2-way bank-aliased = free). After one
// barrier, wave w computes col-tile w (16 cols) of the 16x256 output via 4 MFMA.
__global__ void layer1_kernel(const int* __restrict__ off0, const int* __restrict__ esrc0,
                              const unsigned char* __restrict__ x0f,
                              const int* __restrict__ degO1,
                              const unsigned short* __restrict__ W1Tb,
                              const float* __restrict__ b1,
                              unsigned char* __restrict__ h1f) {
    __shared__ unsigned short A[16 * 136];   // bf16, stride 136 (272B)
    __shared__ float s_out[16];
    int t = threadIdx.x;
    int row0 = blockIdx.x * 16;
    int w = t >> 6, lane = t & 63;
    int half = lane >> 5, l = lane & 31;
    if (t < 16) s_out[t] = rsqrtf(fmaxf((float)degO1[row0 + t], 1.0f)) * H1S;
    // ---- agg phase: wave w -> dst row0 + w ----
    {
        int d = row0 + w;
        int lo = off0[d], hi = off0[d + 1];
        const unsigned* x4 = (const unsigned*)x0f;     // row = 32 uints
        f32x2 a01a = {0.f, 0.f}, a23a = {0.f, 0.f};
        f32x2 a01b = {0.f, 0.f}, a23b = {0.f, 0.f};
        int j = lo + half;
        for (; j + 2 < hi; j += 4) {                   // 4 loads in flight/wave
            unsigned va = x4[esrc0[j] * 32 + l];
            unsigned vb = x4[esrc0[j + 2] * 32 + l];
            a01a += up_lo(va); a23a += up_hi(va);
            a01b += up_lo(vb); a23b += up_hi(vb);
        }
        if (j < hi) {
            unsigned v = x4[esrc0[j] * 32 + l];
            a01a += up_lo(v); a23a += up_hi(v);
        }
        f32x2 a01 = a01a + a01b, a23 = a23a + a23b;
        a01.x += __shfl_down(a01.x, 32); a01.y += __shfl_down(a01.y, 32);
        a23.x += __shfl_down(a23.x, 32); a23.y += __shfl_down(a23.y, 32);
        if (half == 0) {
            float sc = rsqrtf(fmaxf((float)(hi - lo), 1.0f)) * (1.0f / X0S);
            uint2 o; o.x = pack2(a01.x * sc, a01.y * sc); o.y = pack2(a23.x * sc, a23.y * sc);
            *(uint2*)(A + w * 136 + l * 4) = o;        // 4 bf16 per lane
        }
    }
    __syncthreads();
    // ---- gemm phase: wave w -> col tile w (cols 16w..16w+15) ----
    int m = lane & 15, quad = lane >> 4;
    bf16x8 afr[4];
    #pragma unroll
    for (int ks = 0; ks < 4; ++ks)
        afr[ks] = *(const bf16x8*)(A + m * 136 + quad * 8 + ks * 32);
    int gcol0 = w * 16;
    const unsigned short* bbase = W1Tb + (gcol0 + m) * 128 + quad * 8;
    f32x4 acc = {0.f, 0.f, 0.f, 0.f};
    #pragma unroll
    for (int ks = 0; ks < 4; ++ks) {
        bf16x8 bfr = *(const bf16x8*)(bbase + ks * 32);
        acc = __builtin_amdgcn_mfma_f32_16x16x32_bf16(afr[ks], bfr, acc, 0, 0, 0);
    }
    int gcol = gcol0 + m;
    float bb = b1[gcol];
    #pragma unroll
    for (int reg = 0; reg < 4; ++reg) {
        int row = quad * 4 + reg;
        h1f[(row0 + row) * 256 + gcol] = f2fp8(fmaxf(acc[reg] + bb, 0.f) * s_out[row]);
    }
}

// ---------------- layer2: agg (16 waves, 1 dst/wave) + MFMA GEMM (+ labels), fused ----
__global__ void layer2_kernel(const int* __restrict__ off1, const int* __restrict__ esrc1,
                              const unsigned char* __restrict__ h1f,
                              const unsigned short* __restrict__ W2Tb,
                              const float* __restrict__ b2,
                              const int* __restrict__ labels,
                              float* __restrict__ out) {
    __shared__ unsigned short A[16 * 264];   // bf16 rows of 256, stride 264 (528B)
    int t = threadIdx.x;
    int row0 = blockIdx.x * 16;
    int w = t >> 6, lane = t & 63;
    // ---- agg phase: wave w -> dst row0 + w (64 lanes x uint = 256 fp8 row) ----
    {
        int d = row0 + w;
        f32x2 a01 = {0.f, 0.f}, a23 = {0.f, 0.f};
        float sc = 0.f;
        if (d < NDST1) {
            int lo = off1[d], hi = off1[d + 1];
            const unsigned* h4 = (const unsigned*)h1f;     // row = 64 uints
            int j = lo;
            for (; j + 3 < hi; j += 4) {                   // 4 loads in flight
                unsigned v0 = h4[esrc1[j] * 64 + lane];
                unsigned v1 = h4[esrc1[j + 1] * 64 + lane];
                unsigned v2 = h4[esrc1[j + 2] * 64 + lane];
                unsigned v3 = h4[esrc1[j + 3] * 64 + lane];
                a01 += up_lo(v0) + up_lo(v1) + up_lo(v2) + up_lo(v3);
                a23 += up_hi(v0) + up_hi(v1) + up_hi(v2) + up_hi(v3);
            }
            for (; j < hi; ++j) {
                unsigned v = h4[esrc1[j] * 64 + lane];
                a01 += up_lo(v); a23 += up_hi(v);
            }
            sc = rsqrtf(fmaxf((float)(hi - lo), 1.0f)) * (1.0f / H1S);
        }
        uint2 o; o.x = pack2(a01.x * sc, a01.y * sc); o.y = pack2(a23.x * sc, a23.y * sc);
        *(uint2*)(A + w * 264 + lane * 4) = o;
    }
    __syncthreads();
    if (w == 0) {                        // ---- gemm phase: single 16x16 tile ----
        int m = lane & 15, quad = lane >> 4;
        const unsigned short* bbase = W2Tb + m * 256 + quad * 8;
        f32x4 acc = {0.f, 0.f, 0.f, 0.f};
        #pragma unroll
        for (int ks = 0; ks < 8; ++ks) {
            bf16x8 af = *(const bf16x8*)(A + m * 264 + quad * 8 + ks * 32);
            bf16x8 bf = *(const bf16x8*)(bbase + ks * 32);
            acc = __builtin_amdgcn_mfma_f32_16x16x32_bf16(af, bf, acc, 0, 0, 0);
        }
        float bb = b2[m];
        #pragma unroll
        for (int reg = 0; reg < 4; ++reg) {
            int row = row0 + quad * 4 + reg;
            if (row < NDST1)
                out[row * NOUT + m] = fmaxf(acc[reg] + bb, 0.f);
        }
        if (lane < 16 && row0 + lane < NDST1)
            out[NDST1 * NOUT + row0 + lane] = (float)labels[row0 + lane];
    }
}

extern "C" void kernel_launch(void* const* d_in, const int* in_sizes, int n_in,
                              void* d_out, int out_size, void* d_ws, size_t ws_size,
                              hipStream_t stream) {
    const int*   user_word  = (const int*)d_in[0];
    const int*   labels     = (const int*)d_in[1];
    const int*   src0       = (const int*)d_in[2];
    const int*   dst0       = (const int*)d_in[3];
    const int*   src1       = (const int*)d_in[4];
    const int*   dst1       = (const int*)d_in[5];
    const float* word_table = (const float*)d_in[6];
    const float* W1         = (const float*)d_in[7];
    const float* b1         = (const float*)d_in[8];
    const float* W2         = (const float*)d_in[9];
    const float* b2         = (const float*)d_in[10];

    int* iws = (int*)d_ws;
    int* cnt0  = iws;            // 20000  ┐
    int* cnt1  = iws + 20000;    //  5000  │ zeroed (95000 ints)
    int* degO0 = iws + 25000;    // 50000  │
    int* degO1 = iws + 75000;    // 20000  ┘
    int* off0  = iws + 95000;    // 20001
    int* off1  = iws + 115001;   //  5001
    int* cur0  = iws + 120002;   // 20000
    int* cur1  = iws + 140002;   //  5000
    int* esrc0 = iws + 145002;   // 300000
    int* esrc1 = iws + 445002;   // 75000   (end 520002; pad to 520004)
    unsigned char*  wt8  = (unsigned char*)(iws + 520004);   // 6.4M fp8  = 1.6M ints
    unsigned char*  x0f  = (unsigned char*)(iws + 2120004);  // 6.4M fp8  = 1.6M ints
    unsigned char*  h1f  = (unsigned char*)(iws + 3720004);  // 5.12M fp8 = 1.28M ints
    unsigned short* W1Tb = (unsigned short*)(iws + 5000004); // 32768 bf16 = 8192 ints
    unsigned short* W2Tb = (unsigned short*)(iws + 5008196); // 4096 bf16 (end ≈ 20 MB)

    hipMemsetAsync(iws, 0, 95000 * sizeof(int), stream);

    prep_kernel<<<(NSRC0 * EMB / 8 + 255) / 256, 256, 0, stream>>>(
        word_table, wt8, W1, W1Tb, W2, W2Tb,
        src0, dst0, src1, dst1, cnt0, cnt1, degO0, degO1);
    scan_kernel<<<2, 1024, 0, stream>>>(cnt0, off0, cur0, cnt1, off1, cur1);
    embed_bucket_kernel<<<NEMB_BLK * 2, 256, 0, stream>>>(
        user_word, wt8, degO0, x0f,
        src0, dst0, src1, dst1, cur0, cur1, esrc0, esrc1);
    layer1_kernel<<<NDST0 / 16, 1024, 0, stream>>>(off0, esrc0, x0f, degO1, W1Tb, b1, h1f);
    layer2_kernel<<<(NDST1 + 15) / 16, 1024, 0, stream>>>(off1, esrc1, h1f, W2Tb, b2,
                                                          labels, (float*)d_out);
}